// Round 4
// baseline (184.641 us; speedup 1.0000x reference)
//
#include <hip/hip_runtime.h>
#include <cfloat>

#define NN   1024
#define NE   16384
#define D0   128
#define EDIM 16
#define NH1  64
#define NOUT 40
#define KTOP 8
#define NEGINF (-1000000000.0f)
#define MAXDEG 64   // gumbel in-degree ~ Poisson(8); P(>64) astronomically small

// ---- workspace layout (bytes); everything written before read, no memsets ----
#define OFF_SE    0u        // NE f
#define OFF_A     65536u    // 1024 f
#define OFF_B     69632u    // 1024 f
#define OFF_DST   73728u    // 8192 int
#define OFF_EM    106496u   // 8192 int
#define OFF_RS    139264u   // 1025 int (src-csr row starts)
#define OFF_SLOT  143616u   // NE int  (src-csr edge ids)
#define OFF_CNTD  209152u   // 1024 int (dst list counts)
#define OFF_SLOTD 213248u   // 1024*64 int (dst lists, fixed stride)
#define OFF_H     475392u   // 1024*64 f

__device__ __forceinline__ void amx(float& v, int& j, float ov, int oj) {
    if (ov > v || (ov == v && oj < j)) { v = ov; j = oj; }
}

// blocks 0..63: se[e]=ea[e]@w_e ; blocks 64..319: a,b row dots ;
// block 320: src-CSR build (count -> scan -> fill) + zero cntd.
__global__ __launch_bounds__(256) void prep_kernel(
    const float* __restrict__ x, const float* __restrict__ ea,
    const float* __restrict__ mlp_w, const int* __restrict__ ei,
    float* __restrict__ se, float* __restrict__ a, float* __restrict__ b,
    int* __restrict__ rs_src, int* __restrict__ slot_src, int* __restrict__ cntd)
{
    const int bid = blockIdx.x, t = threadIdx.x;
    if (bid < 64) {
        int e = bid * 256 + t;
        float acc = 0.f;
        #pragma unroll
        for (int k = 0; k < EDIM; k++) acc += ea[e * EDIM + k] * mlp_w[2 * D0 + k];
        se[e] = acc;
    } else if (bid < 320) {
        int lane = t & 63, wid = t >> 6;
        int row = (bid - 64) * 4 + wid;
        const float* xr = x + row * D0;
        float x0 = xr[lane], x1 = xr[64 + lane];
        float sa = x0 * mlp_w[lane]       + x1 * mlp_w[64 + lane];
        float sb = x0 * mlp_w[128 + lane] + x1 * mlp_w[192 + lane];
        for (int s2 = 32; s2; s2 >>= 1) { sa += __shfl_down(sa, s2); sb += __shfl_down(sb, s2); }
        if (lane == 0) { a[row] = sa; b[row] = sb; }
    } else {
        __shared__ int cnts[NN];
        __shared__ int part[256];
        __shared__ int ptr[NN];
        #pragma unroll
        for (int q = 0; q < 4; q++) { cnts[t + q * 256] = 0; cntd[t + q * 256] = 0; }
        __syncthreads();
        for (int e = t; e < NE; e += 256) atomicAdd(&cnts[ei[e]], 1);
        __syncthreads();
        int base = t * 4;
        int s0 = cnts[base], s1 = cnts[base + 1], s2 = cnts[base + 2], s3 = cnts[base + 3];
        int tsum = s0 + s1 + s2 + s3;
        part[t] = tsum;
        __syncthreads();
        for (int off = 1; off < 256; off <<= 1) {
            int add = (t >= off) ? part[t - off] : 0;
            __syncthreads();
            part[t] += add;
            __syncthreads();
        }
        int r0 = part[t] - tsum;
        int r1 = r0 + s0, r2 = r1 + s1, r3 = r2 + s2;
        rs_src[base] = r0; rs_src[base + 1] = r1; rs_src[base + 2] = r2; rs_src[base + 3] = r3;
        ptr[base] = r0; ptr[base + 1] = r1; ptr[base + 2] = r2; ptr[base + 3] = r3;
        if (t == 255) rs_src[NN] = NE;
        __syncthreads();
        for (int e = t; e < NE; e += 256) {
            int p = atomicAdd(&ptr[ei[e]], 1);
            slot_src[p] = e;   // row order nondeterministic; consumers use max/min only
        }
    }
}

// Per row i: rebuild idmax/idmin for this row's ~16 edges in LDS (order-independent),
// masked softmax, +gumbel, top-8, append selections to per-dst lists.
__global__ __launch_bounds__(256) void row_topk_kernel(
    const float* __restrict__ se, const float* __restrict__ mlp_b,
    const float* __restrict__ a, const float* __restrict__ b,
    const float* __restrict__ u, const int* __restrict__ ei,
    const int* __restrict__ rs_src, const int* __restrict__ slot_src,
    int* __restrict__ dsti, int* __restrict__ em,
    int* __restrict__ cntd, int* __restrict__ slotd)
{
    __shared__ float sv[NN];
    __shared__ int   idmx[NN];
    __shared__ int   idmn[NN];
    __shared__ float wred[4];
    __shared__ int   wredj[4];
    __shared__ int   selj[KTOP];
    const int i = blockIdx.x, t = threadIdx.x;
    const int lane = t & 63, wid = t >> 6;
    const int rowoff = i * NN;
    const float bias = mlp_b[0];
    const float ai = a[i];

    #pragma unroll
    for (int q = 0; q < 4; q++) { int j = t + q * 256; idmx[j] = -1; idmn[j] = 0x7FFFFFFF; }
    __syncthreads();
    int beg = rs_src[i], end = rs_src[i + 1];
    for (int p = beg + t; p < end; p += 256) {
        int e = slot_src[p];
        int dj = ei[NE + e];
        atomicMax(&idmx[dj], e);
        atomicMin(&idmn[dj], e);
    }
    __syncthreads();

    float lmax = NEGINF;
    #pragma unroll
    for (int q = 0; q < 4; q++) {
        int j = t + q * 256;
        int id = idmx[j];
        float s = (id >= 0) ? (((ai + b[j]) + se[id]) + bias) : NEGINF;
        sv[j] = s;
        lmax = fmaxf(lmax, s);
    }
    for (int s = 32; s; s >>= 1) lmax = fmaxf(lmax, __shfl_down(lmax, s));
    if (lane == 0) wred[wid] = lmax;
    __syncthreads();
    float rowmax = fmaxf(fmaxf(wred[0], wred[1]), fmaxf(wred[2], wred[3]));
    bool noedge = (rowmax == NEGINF);
    __syncthreads();

    float lsum = 0.f;
    #pragma unroll
    for (int q = 0; q < 4; q++) {
        int j = t + q * 256;
        float evv;
        if (noedge) evv = 1.0f;
        else { float s = sv[j]; evv = (s == NEGINF) ? 0.0f : expf(s - rowmax); }
        sv[j] = evv;
        lsum += evv;
    }
    for (int s = 32; s; s >>= 1) lsum += __shfl_down(lsum, s);
    if (lane == 0) wred[wid] = lsum;
    __syncthreads();
    float rsum = wred[0] + wred[1] + wred[2] + wred[3];
    __syncthreads();

    #pragma unroll
    for (int q = 0; q < 4; q++) {
        int j = t + q * 256;
        float z = sv[j] / rsum;
        float uu = u[rowoff + j];
        float g = -logf(-logf(uu + 1e-20f) + 1e-20f);
        sv[j] = z + g;
    }
    __syncthreads();

    for (int sel = 0; sel < KTOP; sel++) {
        float bv = -FLT_MAX; int bj = NN;
        #pragma unroll
        for (int q = 0; q < 4; q++) { int j = t + q * 256; amx(bv, bj, sv[j], j); }
        for (int s = 32; s; s >>= 1) {
            float ov = __shfl_down(bv, s); int oj = __shfl_down(bj, s);
            amx(bv, bj, ov, oj);
        }
        if (lane == 0) { wred[wid] = bv; wredj[wid] = bj; }
        __syncthreads();
        if (t == 0) {
            float v = wred[0]; int j = wredj[0];
            amx(v, j, wred[1], wredj[1]);
            amx(v, j, wred[2], wredj[2]);
            amx(v, j, wred[3], wredj[3]);
            selj[sel] = j;
            dsti[i * KTOP + sel] = j;
            int mn = idmn[j];
            em[i * KTOP + sel] = (mn == 0x7FFFFFFF) ? 0 : mn;
            sv[j] = -FLT_MAX;
        }
        __syncthreads();
    }
    if (t < KTOP) {
        int j = selj[t];
        int n = i * KTOP + t;
        int p = atomicAdd(&cntd[j], 1);
        if (p < MAXDEG) slotd[j * MAXDEG + p] = n;
    }
}

// GENConv1 fused: 2 dst nodes per 256-thread block. d = t&127, sub = t>>7.
__global__ __launch_bounds__(256) void genconv1_kernel(
    const float* __restrict__ x, const float* __restrict__ ea,
    const float* __restrict__ we_g, const float* __restrict__ be,
    const float* __restrict__ w1, const float* __restrict__ b1,
    const float* __restrict__ w2, const float* __restrict__ b2,
    const int* __restrict__ cntd, const int* __restrict__ slotd,
    const int* __restrict__ em, float* __restrict__ h)
{
    __shared__ int   slots[2][MAXDEG];
    __shared__ float eatt[2][MAXDEG * EDIM];
    __shared__ float arow[2][D0];
    __shared__ float t1s[2][2 * D0];
    const int t = threadIdx.x, sub = t >> 7, d = t & 127;
    const int r = blockIdx.x * 2 + sub;
    const int cnt = min(cntd[r], MAXDEG);
    if (d < cnt) slots[sub][d] = slotd[r * MAXDEG + d];
    __syncthreads();
    if (d == 0) {  // ascending-n order (deterministic)
        for (int p = 1; p < cnt; p++) {
            int v = slots[sub][p]; int q = p - 1;
            while (q >= 0 && slots[sub][q] > v) { slots[sub][q + 1] = slots[sub][q]; q--; }
            slots[sub][q + 1] = v;
        }
    }
    __syncthreads();
    for (int q = d; q < cnt * EDIM; q += 128)
        eatt[sub][q] = ea[em[slots[sub][q >> 4]] * EDIM + (q & 15)];
    __syncthreads();

    float wed[EDIM];
    #pragma unroll
    for (int k = 0; k < EDIM; k++) wed[k] = we_g[k * D0 + d];
    const float bed = be[d];

    float mxv = -FLT_MAX;
    for (int idx = 0; idx < cnt; idx++) {
        int src = slots[sub][idx] >> 3;
        float ep = bed;
        #pragma unroll
        for (int k = 0; k < EDIM; k++) ep += eatt[sub][idx * EDIM + k] * wed[k];
        float m = fmaxf(x[src * D0 + d] + ep, 0.f) + 1e-7f;
        mxv = fmaxf(mxv, m);
    }
    float den = 0.f, num = 0.f;
    for (int idx = 0; idx < cnt; idx++) {
        int src = slots[sub][idx] >> 3;
        float ep = bed;
        #pragma unroll
        for (int k = 0; k < EDIM; k++) ep += eatt[sub][idx * EDIM + k] * wed[k];
        float m = fmaxf(x[src * D0 + d] + ep, 0.f) + 1e-7f;
        float w = expf(m - mxv);
        den += w; num += w * m;
    }
    float agg = cnt ? num / (den > 0.f ? den : 1.f) : 0.f;
    arow[sub][d] = agg + x[r * D0 + d];
    __syncthreads();

    float acc0 = b1[d], acc1 = b1[d + D0];
    for (int k = 0; k < D0; k++) {
        float av = arow[sub][k];
        acc0 += av * w1[k * 2 * D0 + d];
        acc1 += av * w1[k * 2 * D0 + d + D0];
    }
    t1s[sub][d] = fmaxf(acc0, 0.f);
    t1s[sub][d + D0] = fmaxf(acc1, 0.f);
    __syncthreads();
    if (d < NH1) {
        float acc = b2[d];
        for (int k = 0; k < 2 * D0; k++) acc += t1s[sub][k] * w2[k * NH1 + d];
        h[r * NH1 + d] = fmaxf(acc, 0.f);
    }
}

// GENConv2 fused + head: 4 dst nodes per 256-thread block. d = t&63, sub = t>>6.
__global__ __launch_bounds__(256) void genconv2_kernel(
    const float* __restrict__ h, const float* __restrict__ ea,
    const float* __restrict__ we_g, const float* __restrict__ be,
    const float* __restrict__ w1, const float* __restrict__ b1,
    const float* __restrict__ w2, const float* __restrict__ b2,
    const float* __restrict__ fcw, const float* __restrict__ fcb,
    const int* __restrict__ cntd, const int* __restrict__ slotd,
    const int* __restrict__ em, const int* __restrict__ mask,
    float* __restrict__ out)
{
    __shared__ int   slots[4][MAXDEG];
    __shared__ float eatt[4][MAXDEG * EDIM];
    __shared__ float arow[4][NH1];
    __shared__ float t2s[4][2 * NH1];
    __shared__ float h2s[4][NH1];
    const int t = threadIdx.x, sub = t >> 6, d = t & 63;
    const int r = blockIdx.x * 4 + sub;
    const int cnt = min(cntd[r], MAXDEG);
    if (d < cnt) slots[sub][d] = slotd[r * MAXDEG + d];
    __syncthreads();
    if (d == 0) {
        for (int p = 1; p < cnt; p++) {
            int v = slots[sub][p]; int q = p - 1;
            while (q >= 0 && slots[sub][q] > v) { slots[sub][q + 1] = slots[sub][q]; q--; }
            slots[sub][q + 1] = v;
        }
    }
    __syncthreads();
    for (int q = d; q < cnt * EDIM; q += 64)
        eatt[sub][q] = ea[em[slots[sub][q >> 4]] * EDIM + (q & 15)];
    __syncthreads();

    float wed[EDIM];
    #pragma unroll
    for (int k = 0; k < EDIM; k++) wed[k] = we_g[k * NH1 + d];
    const float bed = be[d];

    float mxv = -FLT_MAX;
    for (int idx = 0; idx < cnt; idx++) {
        int src = slots[sub][idx] >> 3;
        float ep = bed;
        #pragma unroll
        for (int k = 0; k < EDIM; k++) ep += eatt[sub][idx * EDIM + k] * wed[k];
        float m = fmaxf(h[src * NH1 + d] + ep, 0.f) + 1e-7f;
        mxv = fmaxf(mxv, m);
    }
    float den = 0.f, num = 0.f;
    for (int idx = 0; idx < cnt; idx++) {
        int src = slots[sub][idx] >> 3;
        float ep = bed;
        #pragma unroll
        for (int k = 0; k < EDIM; k++) ep += eatt[sub][idx * EDIM + k] * wed[k];
        float m = fmaxf(h[src * NH1 + d] + ep, 0.f) + 1e-7f;
        float w = expf(m - mxv);
        den += w; num += w * m;
    }
    float agg = cnt ? num / (den > 0.f ? den : 1.f) : 0.f;
    arow[sub][d] = agg + h[r * NH1 + d];
    __syncthreads();

    {
        float acc_a = b1[d], acc_b = b1[d + NH1];
        for (int k = 0; k < NH1; k++) {
            float av = arow[sub][k];
            acc_a += av * w1[k * 2 * NH1 + d];
            acc_b += av * w1[k * 2 * NH1 + d + NH1];
        }
        t2s[sub][d] = fmaxf(acc_a, 0.f);
        t2s[sub][d + NH1] = fmaxf(acc_b, 0.f);
    }
    __syncthreads();
    {
        float acc = b2[d];
        for (int k = 0; k < 2 * NH1; k++) acc += t2s[sub][k] * w2[k * NH1 + d];
        h2s[sub][d] = fmaxf(acc, 0.f);
    }
    __syncthreads();
    if (d < NOUT) {
        float acc = fcb[d];
        for (int k = 0; k < NH1; k++) acc += h2s[sub][k] * fcw[k * NOUT + d];
        out[r * NOUT + d] = (mask[r] != 0) ? acc : 0.f;
    }
}

extern "C" void kernel_launch(void* const* d_in, const int* in_sizes, int n_in,
                              void* d_out, int out_size, void* d_ws, size_t ws_size,
                              hipStream_t stream) {
    const float* x      = (const float*)d_in[0];
    const float* ea     = (const float*)d_in[1];
    const float* u      = (const float*)d_in[2];
    const float* mlp_w  = (const float*)d_in[3];
    const float* mlp_b  = (const float*)d_in[4];
    const float* c1_we  = (const float*)d_in[5];
    const float* c1_be  = (const float*)d_in[6];
    const float* c1_w1  = (const float*)d_in[7];
    const float* c1_b1  = (const float*)d_in[8];
    const float* c1_w2  = (const float*)d_in[9];
    const float* c1_b2  = (const float*)d_in[10];
    const float* c2_we  = (const float*)d_in[11];
    const float* c2_be  = (const float*)d_in[12];
    const float* c2_w1  = (const float*)d_in[13];
    const float* c2_b1  = (const float*)d_in[14];
    const float* c2_w2  = (const float*)d_in[15];
    const float* c2_b2  = (const float*)d_in[16];
    const float* fc_w   = (const float*)d_in[17];
    const float* fc_b   = (const float*)d_in[18];
    const int*   ei     = (const int*)d_in[20];
    const int*   mask   = (const int*)d_in[21];

    char* ws = (char*)d_ws;
    float* se      = (float*)(ws + OFF_SE);
    float* a       = (float*)(ws + OFF_A);
    float* b       = (float*)(ws + OFF_B);
    int*   dsti    = (int*)(ws + OFF_DST);
    int*   em      = (int*)(ws + OFF_EM);
    int*   rs_src  = (int*)(ws + OFF_RS);
    int*   slot_s  = (int*)(ws + OFF_SLOT);
    int*   cntd    = (int*)(ws + OFF_CNTD);
    int*   slotd   = (int*)(ws + OFF_SLOTD);
    float* h       = (float*)(ws + OFF_H);
    float* out     = (float*)d_out;

    prep_kernel<<<321, 256, 0, stream>>>(x, ea, mlp_w, ei, se, a, b, rs_src, slot_s, cntd);
    row_topk_kernel<<<NN, 256, 0, stream>>>(se, mlp_b, a, b, u, ei, rs_src, slot_s,
                                            dsti, em, cntd, slotd);
    genconv1_kernel<<<NN / 2, 256, 0, stream>>>(x, ea, c1_we, c1_be, c1_w1, c1_b1, c1_w2, c1_b2,
                                                cntd, slotd, em, h);
    genconv2_kernel<<<NN / 4, 256, 0, stream>>>(h, ea, c2_we, c2_be, c2_w1, c2_b1, c2_w2, c2_b2,
                                                fc_w, fc_b, cntd, slotd, em, mask, out);
}

// Round 5
// 156.482 us; speedup vs baseline: 1.1799x; 1.1799x over previous
//
#include <hip/hip_runtime.h>
#include <cfloat>

#define NN   1024
#define NE   16384
#define D0   128
#define EDIM 16
#define NH1  64
#define NOUT 40
#define KTOP 8
#define NEGINF (-1000000000.0f)
#define MAXDEG 64   // out-deg ~ Poisson(16), gumbel in-deg ~ Poisson(8); P(>64) ~ 1e-20

// ---- workspace layout (bytes); counters zeroed by one 8KB memset, rest written-before-read ----
#define OFF_CNTS  0u        // 1024 int (src list counts)   \ contiguous 8KB memset
#define OFF_CNTD  4096u     // 1024 int (dst list counts)   /
#define OFF_SE    8192u     // NE f
#define OFF_A     73728u    // 1024 f
#define OFF_B     77824u    // 1024 f
#define OFF_EM    81920u    // 8192 int
#define OFF_SLOTS 114688u   // 1024*64 int (src lists, fixed stride)
#define OFF_SLOTD 376832u   // 1024*64 int (dst lists, fixed stride)
#define OFF_H     638976u   // 1024*64 f

__device__ __forceinline__ void amx(float& v, int& j, float ov, int oj) {
    if (ov > v || (ov == v && oj < j)) { v = ov; j = oj; }
}

// blocks 0..63: se[e]=ea[e]@w_e + scatter edge into per-src list (parallel atomics);
// blocks 64..319: a,b row dots.
__global__ __launch_bounds__(256) void prep_kernel(
    const float* __restrict__ x, const float* __restrict__ ea,
    const float* __restrict__ mlp_w, const int* __restrict__ ei,
    float* __restrict__ se, float* __restrict__ a, float* __restrict__ b,
    int* __restrict__ cnt_src, int* __restrict__ slot_src)
{
    const int bid = blockIdx.x, t = threadIdx.x;
    if (bid < 64) {
        int e = bid * 256 + t;
        float acc = 0.f;
        #pragma unroll
        for (int k = 0; k < EDIM; k++) acc += ea[e * EDIM + k] * mlp_w[2 * D0 + k];
        se[e] = acc;
        int s = ei[e];
        int p = atomicAdd(&cnt_src[s], 1);
        if (p < MAXDEG) slot_src[s * MAXDEG + p] = e;  // order nondeterministic; consumer is max/min
    } else {
        int lane = t & 63, wid = t >> 6;
        int row = (bid - 64) * 4 + wid;
        const float* xr = x + row * D0;
        float x0 = xr[lane], x1 = xr[64 + lane];
        float sa = x0 * mlp_w[lane]       + x1 * mlp_w[64 + lane];
        float sb = x0 * mlp_w[128 + lane] + x1 * mlp_w[192 + lane];
        for (int s2 = 32; s2; s2 >>= 1) { sa += __shfl_down(sa, s2); sb += __shfl_down(sb, s2); }
        if (lane == 0) { a[row] = sa; b[row] = sb; }
    }
}

// Per row i: rebuild idmax/idmin for this row's ~16 edges in LDS (order-independent),
// masked softmax, +gumbel, top-8, append selections to per-dst lists.
__global__ __launch_bounds__(256) void row_topk_kernel(
    const float* __restrict__ se, const float* __restrict__ mlp_b,
    const float* __restrict__ a, const float* __restrict__ b,
    const float* __restrict__ u, const int* __restrict__ ei,
    const int* __restrict__ cnt_src, const int* __restrict__ slot_src,
    int* __restrict__ em, int* __restrict__ cntd, int* __restrict__ slotd)
{
    __shared__ float sv[NN];
    __shared__ int   idmx[NN];
    __shared__ int   idmn[NN];
    __shared__ float wred[4];
    __shared__ int   wredj[4];
    __shared__ int   selj[KTOP];
    const int i = blockIdx.x, t = threadIdx.x;
    const int lane = t & 63, wid = t >> 6;
    const int rowoff = i * NN;
    const float bias = mlp_b[0];
    const float ai = a[i];

    #pragma unroll
    for (int q = 0; q < 4; q++) { int j = t + q * 256; idmx[j] = -1; idmn[j] = 0x7FFFFFFF; }
    __syncthreads();
    int deg = min(cnt_src[i], MAXDEG);
    if (t < deg) {
        int e = slot_src[i * MAXDEG + t];
        int dj = ei[NE + e];
        atomicMax(&idmx[dj], e);
        atomicMin(&idmn[dj], e);
    }
    __syncthreads();

    float lmax = NEGINF;
    #pragma unroll
    for (int q = 0; q < 4; q++) {
        int j = t + q * 256;
        int id = idmx[j];
        float s = (id >= 0) ? (((ai + b[j]) + se[id]) + bias) : NEGINF;
        sv[j] = s;
        lmax = fmaxf(lmax, s);
    }
    for (int s = 32; s; s >>= 1) lmax = fmaxf(lmax, __shfl_down(lmax, s));
    if (lane == 0) wred[wid] = lmax;
    __syncthreads();
    float rowmax = fmaxf(fmaxf(wred[0], wred[1]), fmaxf(wred[2], wred[3]));
    bool noedge = (rowmax == NEGINF);
    __syncthreads();

    float lsum = 0.f;
    #pragma unroll
    for (int q = 0; q < 4; q++) {
        int j = t + q * 256;
        float evv;
        if (noedge) evv = 1.0f;
        else { float s = sv[j]; evv = (s == NEGINF) ? 0.0f : expf(s - rowmax); }
        sv[j] = evv;
        lsum += evv;
    }
    for (int s = 32; s; s >>= 1) lsum += __shfl_down(lsum, s);
    if (lane == 0) wred[wid] = lsum;
    __syncthreads();
    float rsum = wred[0] + wred[1] + wred[2] + wred[3];
    __syncthreads();

    #pragma unroll
    for (int q = 0; q < 4; q++) {
        int j = t + q * 256;
        float z = sv[j] / rsum;
        float uu = u[rowoff + j];
        float g = -logf(-logf(uu + 1e-20f) + 1e-20f);
        sv[j] = z + g;
    }
    __syncthreads();

    for (int sel = 0; sel < KTOP; sel++) {
        float bv = -FLT_MAX; int bj = NN;
        #pragma unroll
        for (int q = 0; q < 4; q++) { int j = t + q * 256; amx(bv, bj, sv[j], j); }
        for (int s = 32; s; s >>= 1) {
            float ov = __shfl_down(bv, s); int oj = __shfl_down(bj, s);
            amx(bv, bj, ov, oj);
        }
        if (lane == 0) { wred[wid] = bv; wredj[wid] = bj; }
        __syncthreads();
        if (t == 0) {
            float v = wred[0]; int j = wredj[0];
            amx(v, j, wred[1], wredj[1]);
            amx(v, j, wred[2], wredj[2]);
            amx(v, j, wred[3], wredj[3]);
            selj[sel] = j;
            int mn = idmn[j];
            em[i * KTOP + sel] = (mn == 0x7FFFFFFF) ? 0 : mn;
            sv[j] = -FLT_MAX;
        }
        __syncthreads();
    }
    if (t < KTOP) {
        int j = selj[t];
        int n = i * KTOP + t;
        int p = atomicAdd(&cntd[j], 1);
        if (p < MAXDEG) slotd[j * MAXDEG + p] = n;
    }
}

// GENConv1 fused: 2 dst nodes per 256-thread block. d = t&127, sub = t>>7.
__global__ __launch_bounds__(256) void genconv1_kernel(
    const float* __restrict__ x, const float* __restrict__ ea,
    const float* __restrict__ we_g, const float* __restrict__ be,
    const float* __restrict__ w1, const float* __restrict__ b1,
    const float* __restrict__ w2, const float* __restrict__ b2,
    const int* __restrict__ cntd, const int* __restrict__ slotd,
    const int* __restrict__ em, float* __restrict__ h)
{
    __shared__ int   slots[2][MAXDEG];
    __shared__ float eatt[2][MAXDEG * EDIM];
    __shared__ float arow[2][D0];
    __shared__ float t1s[2][2 * D0];
    const int t = threadIdx.x, sub = t >> 7, d = t & 127;
    const int r = blockIdx.x * 2 + sub;
    const int cnt = min(cntd[r], MAXDEG);
    if (d < cnt) slots[sub][d] = slotd[r * MAXDEG + d];
    __syncthreads();
    if (d == 0) {  // ascending-n order (deterministic)
        for (int p = 1; p < cnt; p++) {
            int v = slots[sub][p]; int q = p - 1;
            while (q >= 0 && slots[sub][q] > v) { slots[sub][q + 1] = slots[sub][q]; q--; }
            slots[sub][q + 1] = v;
        }
    }
    __syncthreads();
    for (int q = d; q < cnt * EDIM; q += 128)
        eatt[sub][q] = ea[em[slots[sub][q >> 4]] * EDIM + (q & 15)];
    __syncthreads();

    float wed[EDIM];
    #pragma unroll
    for (int k = 0; k < EDIM; k++) wed[k] = we_g[k * D0 + d];
    const float bed = be[d];

    float mxv = -FLT_MAX;
    for (int idx = 0; idx < cnt; idx++) {
        int src = slots[sub][idx] >> 3;
        float ep = bed;
        #pragma unroll
        for (int k = 0; k < EDIM; k++) ep += eatt[sub][idx * EDIM + k] * wed[k];
        float m = fmaxf(x[src * D0 + d] + ep, 0.f) + 1e-7f;
        mxv = fmaxf(mxv, m);
    }
    float den = 0.f, num = 0.f;
    for (int idx = 0; idx < cnt; idx++) {
        int src = slots[sub][idx] >> 3;
        float ep = bed;
        #pragma unroll
        for (int k = 0; k < EDIM; k++) ep += eatt[sub][idx * EDIM + k] * wed[k];
        float m = fmaxf(x[src * D0 + d] + ep, 0.f) + 1e-7f;
        float w = expf(m - mxv);
        den += w; num += w * m;
    }
    float agg = cnt ? num / (den > 0.f ? den : 1.f) : 0.f;
    arow[sub][d] = agg + x[r * D0 + d];
    __syncthreads();

    float acc0 = b1[d], acc1 = b1[d + D0];
    for (int k = 0; k < D0; k++) {
        float av = arow[sub][k];
        acc0 += av * w1[k * 2 * D0 + d];
        acc1 += av * w1[k * 2 * D0 + d + D0];
    }
    t1s[sub][d] = fmaxf(acc0, 0.f);
    t1s[sub][d + D0] = fmaxf(acc1, 0.f);
    __syncthreads();
    if (d < NH1) {
        float acc = b2[d];
        for (int k = 0; k < 2 * D0; k++) acc += t1s[sub][k] * w2[k * NH1 + d];
        h[r * NH1 + d] = fmaxf(acc, 0.f);
    }
}

// GENConv2 fused + head: 4 dst nodes per 256-thread block. d = t&63, sub = t>>6.
__global__ __launch_bounds__(256) void genconv2_kernel(
    const float* __restrict__ h, const float* __restrict__ ea,
    const float* __restrict__ we_g, const float* __restrict__ be,
    const float* __restrict__ w1, const float* __restrict__ b1,
    const float* __restrict__ w2, const float* __restrict__ b2,
    const float* __restrict__ fcw, const float* __restrict__ fcb,
    const int* __restrict__ cntd, const int* __restrict__ slotd,
    const int* __restrict__ em, const int* __restrict__ mask,
    float* __restrict__ out)
{
    __shared__ int   slots[4][MAXDEG];
    __shared__ float eatt[4][MAXDEG * EDIM];
    __shared__ float arow[4][NH1];
    __shared__ float t2s[4][2 * NH1];
    __shared__ float h2s[4][NH1];
    const int t = threadIdx.x, sub = t >> 6, d = t & 63;
    const int r = blockIdx.x * 4 + sub;
    const int cnt = min(cntd[r], MAXDEG);
    if (d < cnt) slots[sub][d] = slotd[r * MAXDEG + d];
    __syncthreads();
    if (d == 0) {
        for (int p = 1; p < cnt; p++) {
            int v = slots[sub][p]; int q = p - 1;
            while (q >= 0 && slots[sub][q] > v) { slots[sub][q + 1] = slots[sub][q]; q--; }
            slots[sub][q + 1] = v;
        }
    }
    __syncthreads();
    for (int q = d; q < cnt * EDIM; q += 64)
        eatt[sub][q] = ea[em[slots[sub][q >> 4]] * EDIM + (q & 15)];
    __syncthreads();

    float wed[EDIM];
    #pragma unroll
    for (int k = 0; k < EDIM; k++) wed[k] = we_g[k * NH1 + d];
    const float bed = be[d];

    float mxv = -FLT_MAX;
    for (int idx = 0; idx < cnt; idx++) {
        int src = slots[sub][idx] >> 3;
        float ep = bed;
        #pragma unroll
        for (int k = 0; k < EDIM; k++) ep += eatt[sub][idx * EDIM + k] * wed[k];
        float m = fmaxf(h[src * NH1 + d] + ep, 0.f) + 1e-7f;
        mxv = fmaxf(mxv, m);
    }
    float den = 0.f, num = 0.f;
    for (int idx = 0; idx < cnt; idx++) {
        int src = slots[sub][idx] >> 3;
        float ep = bed;
        #pragma unroll
        for (int k = 0; k < EDIM; k++) ep += eatt[sub][idx * EDIM + k] * wed[k];
        float m = fmaxf(h[src * NH1 + d] + ep, 0.f) + 1e-7f;
        float w = expf(m - mxv);
        den += w; num += w * m;
    }
    float agg = cnt ? num / (den > 0.f ? den : 1.f) : 0.f;
    arow[sub][d] = agg + h[r * NH1 + d];
    __syncthreads();

    {
        float acc_a = b1[d], acc_b = b1[d + NH1];
        for (int k = 0; k < NH1; k++) {
            float av = arow[sub][k];
            acc_a += av * w1[k * 2 * NH1 + d];
            acc_b += av * w1[k * 2 * NH1 + d + NH1];
        }
        t2s[sub][d] = fmaxf(acc_a, 0.f);
        t2s[sub][d + NH1] = fmaxf(acc_b, 0.f);
    }
    __syncthreads();
    {
        float acc = b2[d];
        for (int k = 0; k < 2 * NH1; k++) acc += t2s[sub][k] * w2[k * NH1 + d];
        h2s[sub][d] = fmaxf(acc, 0.f);
    }
    __syncthreads();
    if (d < NOUT) {
        float acc = fcb[d];
        for (int k = 0; k < NH1; k++) acc += h2s[sub][k] * fcw[k * NOUT + d];
        out[r * NOUT + d] = (mask[r] != 0) ? acc : 0.f;
    }
}

extern "C" void kernel_launch(void* const* d_in, const int* in_sizes, int n_in,
                              void* d_out, int out_size, void* d_ws, size_t ws_size,
                              hipStream_t stream) {
    const float* x      = (const float*)d_in[0];
    const float* ea     = (const float*)d_in[1];
    const float* u      = (const float*)d_in[2];
    const float* mlp_w  = (const float*)d_in[3];
    const float* mlp_b  = (const float*)d_in[4];
    const float* c1_we  = (const float*)d_in[5];
    const float* c1_be  = (const float*)d_in[6];
    const float* c1_w1  = (const float*)d_in[7];
    const float* c1_b1  = (const float*)d_in[8];
    const float* c1_w2  = (const float*)d_in[9];
    const float* c1_b2  = (const float*)d_in[10];
    const float* c2_we  = (const float*)d_in[11];
    const float* c2_be  = (const float*)d_in[12];
    const float* c2_w1  = (const float*)d_in[13];
    const float* c2_b1  = (const float*)d_in[14];
    const float* c2_w2  = (const float*)d_in[15];
    const float* c2_b2  = (const float*)d_in[16];
    const float* fc_w   = (const float*)d_in[17];
    const float* fc_b   = (const float*)d_in[18];
    const int*   ei     = (const int*)d_in[20];
    const int*   mask   = (const int*)d_in[21];

    char* ws = (char*)d_ws;
    int*   cnt_src = (int*)(ws + OFF_CNTS);
    int*   cntd    = (int*)(ws + OFF_CNTD);
    float* se      = (float*)(ws + OFF_SE);
    float* a       = (float*)(ws + OFF_A);
    float* b       = (float*)(ws + OFF_B);
    int*   em      = (int*)(ws + OFF_EM);
    int*   slot_s  = (int*)(ws + OFF_SLOTS);
    int*   slotd   = (int*)(ws + OFF_SLOTD);
    float* h       = (float*)(ws + OFF_H);
    float* out     = (float*)d_out;

    hipMemsetAsync(ws + OFF_CNTS, 0, 8192, stream);  // cnt_src + cntd
    prep_kernel<<<320, 256, 0, stream>>>(x, ea, mlp_w, ei, se, a, b, cnt_src, slot_s);
    row_topk_kernel<<<NN, 256, 0, stream>>>(se, mlp_b, a, b, u, ei, cnt_src, slot_s,
                                            em, cntd, slotd);
    genconv1_kernel<<<NN / 2, 256, 0, stream>>>(x, ea, c1_we, c1_be, c1_w1, c1_b1, c1_w2, c1_b2,
                                                cntd, slotd, em, h);
    genconv2_kernel<<<NN / 4, 256, 0, stream>>>(h, ea, c2_we, c2_be, c2_w1, c2_b1, c2_w2, c2_b2,
                                                fc_w, fc_b, cntd, slotd, em, mask, out);
}